// Round 4
// baseline (268.201 us; speedup 1.0000x reference)
//
#include <hip/hip_runtime.h>

typedef __bf16 bf16x8 __attribute__((ext_vector_type(8)));
typedef float  f32x4  __attribute__((ext_vector_type(4)));

#define K_SCALE 0.25505402682247326f  // log2(e)/sqrt(32), folded into Wk/bk

static __device__ __forceinline__ unsigned short f2bf(float f) {
  return __builtin_bit_cast(unsigned short, (__bf16)f);
}
static __device__ __forceinline__ f32x4 mfma16(bf16x8 a, bf16x8 b, f32x4 c) {
  return __builtin_amdgcn_mfma_f32_16x16x32_bf16(a, b, c, 0, 0, 0);
}

// ---- prep: W -> bf16 in MFMA B-fragment order (K pre-scaled); bias concat --
__global__ __launch_bounds__(256) void prep_kernel(
    const float* __restrict__ Wq, const float* __restrict__ bq,
    const float* __restrict__ Wk, const float* __restrict__ bk,
    const float* __restrict__ Wv, const float* __restrict__ bv,
    unsigned short* __restrict__ Wf, float* __restrict__ bias) {
  if (blockIdx.x == 96) {
    int t = threadIdx.x;
#pragma unroll
    for (int kseg = 0; kseg < 3; ++kseg) {
      int i = kseg * 256 + t;
      float bb;
      if (i < 256)      bb = bq[i];
      else if (i < 512) bb = bk[i - 256] * K_SCALE;
      else              bb = bv[i - 512];
      bias[i] = bb;
    }
    return;
  }
  int fidx = blockIdx.x * 256 + threadIdx.x;  // < 24576
  int lane = fidx & 63;
  int ks = (fidx >> 6) & 7;
  int ct = fidx >> 9;
  int n = ct * 16 + (lane & 15);
  int kk = ks * 32 + (lane >> 4) * 8;
  const float* src;
  float scale = 1.0f;
  if (n < 256)      src = Wq + n * 256 + kk;
  else if (n < 512) { src = Wk + (n - 256) * 256 + kk; scale = K_SCALE; }
  else              src = Wv + (n - 512) * 256 + kk;
  float4 f0 = reinterpret_cast<const float4*>(src)[0];
  float4 f1 = reinterpret_cast<const float4*>(src)[1];
  bf16x8 h;
  h[0] = (__bf16)(f0.x * scale); h[1] = (__bf16)(f0.y * scale);
  h[2] = (__bf16)(f0.z * scale); h[3] = (__bf16)(f0.w * scale);
  h[4] = (__bf16)(f1.x * scale); h[5] = (__bf16)(f1.y * scale);
  h[6] = (__bf16)(f1.z * scale); h[7] = (__bf16)(f1.w * scale);
  *reinterpret_cast<bf16x8*>(Wf + fidx * 8) = h;
}

// ---- qkv: C[16384x768] = X @ W^T. Q->fp32 d_out; K->[bh][n][pd] bf16;
//      V->[bh][d][pn] bf16. Wave = 32 rows x 6 col-tiles. ---------------------
__global__ __launch_bounds__(512, 4) void qkv_kernel(
    const float* __restrict__ X, const unsigned short* __restrict__ Wf,
    const float* __restrict__ bias, float* __restrict__ Qout,
    unsigned short* __restrict__ Kb, unsigned short* __restrict__ Vt) {
  __shared__ __align__(16) unsigned short Alds[32 * 256];
  const int tid = threadIdx.x;
  const int rowbase = blockIdx.x * 32;
  {  // stage A tile 32x256 fp32->bf16, XOR chunk swizzle
    int idx = tid * 16;
    int r = idx >> 8, k = idx & 255;
    const float4* src = reinterpret_cast<const float4*>(X + (rowbase + r) * 256 + k);
    float4 f0 = src[0], f1 = src[1], f2 = src[2], f3 = src[3];
    bf16x8 h0, h1;
    h0[0]=(__bf16)f0.x; h0[1]=(__bf16)f0.y; h0[2]=(__bf16)f0.z; h0[3]=(__bf16)f0.w;
    h0[4]=(__bf16)f1.x; h0[5]=(__bf16)f1.y; h0[6]=(__bf16)f1.z; h0[7]=(__bf16)f1.w;
    h1[0]=(__bf16)f2.x; h1[1]=(__bf16)f2.y; h1[2]=(__bf16)f2.z; h1[3]=(__bf16)f2.w;
    h1[4]=(__bf16)f3.x; h1[5]=(__bf16)f3.y; h1[6]=(__bf16)f3.z; h1[7]=(__bf16)f3.w;
    int c0 = k >> 3;
    int p0 = (c0 & 24) | ((c0 ^ r) & 7);
    int p1 = ((c0 + 1) & 24) | (((c0 + 1) ^ r) & 7);
    *reinterpret_cast<bf16x8*>(&Alds[r * 256 + p0 * 8]) = h0;
    *reinterpret_cast<bf16x8*>(&Alds[r * 256 + p1 * 8]) = h1;
  }
  __syncthreads();
  const int w = tid >> 6, lane = tid & 63, c = lane & 15, quad = lane >> 4;
  const f32x4 zf = {0.f, 0.f, 0.f, 0.f};
  for (int p = 0; p < 6; ++p) {
    int ct = w * 6 + p;
    f32x4 acc[2] = {zf, zf};
#pragma unroll
    for (int ks = 0; ks < 8; ++ks) {
      bf16x8 bf = *reinterpret_cast<const bf16x8*>(Wf + ((ct * 8 + ks) * 64 + lane) * 8);
#pragma unroll
      for (int mg = 0; mg < 2; ++mg) {
        int m = mg * 16 + c;
        int c8 = ks * 4 + quad;
        int ph = (c8 & 24) | ((c8 ^ m) & 7);
        bf16x8 af = *reinterpret_cast<const bf16x8*>(&Alds[m * 256 + ph * 8]);
        acc[mg] = mfma16(af, bf, acc[mg]);
      }
    }
    int col = ct * 16 + c;
    float bb = bias[col];
#pragma unroll
    for (int mg = 0; mg < 2; ++mg) {
      int growb = rowbase + mg * 16 + quad * 4;
      int b = growb >> 9, nrow = growb & 511;
      if (col < 256) {
#pragma unroll
        for (int r = 0; r < 4; ++r)
          Qout[(growb + r) * 256 + col] = acc[mg][r] + bb;
      } else if (col < 512) {
        int d = col & 31, hh = (col - 256) >> 5;
        int pd = ((d >> 2) & 3) * 8 + ((d >> 4) & 1) * 4 + (d & 3);
#pragma unroll
        for (int r = 0; r < 4; ++r)
          Kb[((b * 8 + hh) * 512 + nrow + r) * 32 + pd] = f2bf(acc[mg][r] + bb);
      } else {
        int d = col & 31, hh = (col - 512) >> 5;
        // key perm: pn = (n&~31) + ((n>>2)&3)*8 + ((n>>4)&1)*4 + (n&3)
        int pnb = (nrow & ~31) + ((nrow >> 2) & 3) * 8 + ((nrow >> 4) & 1) * 4;
        ushort4 pk;
        pk.x = f2bf(acc[mg][0] + bb); pk.y = f2bf(acc[mg][1] + bb);
        pk.z = f2bf(acc[mg][2] + bb); pk.w = f2bf(acc[mg][3] + bb);
        *reinterpret_cast<ushort4*>(&Vt[((b * 8 + hh) * 32 + d) * 512 + pnb]) = pk;
      }
    }
  }
}

// ---- attn: 4 fused layers, transposed MFMA, register-resident state. -------
// grid: 256 bh x 2 segs, 8 waves x 32 queries.
__global__ __launch_bounds__(512, 4) void attn_kernel(
    const float* Q0, const unsigned short* __restrict__ Kg,
    const unsigned short* __restrict__ Vg, float* Out) {
  __shared__ __align__(16) unsigned short Ks[16384];   // [n][slot] 32/row, swz
  __shared__ __align__(16) unsigned short Vts[16384];  // [d][pn] 512/row, swz
  const int tid = threadIdx.x;
  const int bh = blockIdx.x >> 1, seg = blockIdx.x & 1;
  const int b = bh >> 3, h = bh & 7;
  const unsigned short* kgp = Kg + bh * 16384;
  const unsigned short* vgp = Vg + bh * 16384;
#pragma unroll
  for (int it = 0; it < 4; ++it) {
    int idx = it * 4096 + tid * 8;
    {
      int n = idx >> 5, g = (idx >> 3) & 3;
      bf16x8 v = *reinterpret_cast<const bf16x8*>(kgp + idx);
      // slot = g ^ ((n>>1)&3): per 16-lane phase, reads cover all 8 bank
      // groups exactly twice (2-way = free). (c&3-only swizzle was 4-way.)
      *reinterpret_cast<bf16x8*>(&Ks[n * 32 + ((g ^ ((n >> 1) & 3)) << 3)]) = v;
    }
    {
      int d = idx >> 9, nn = idx & 511;
      bf16x8 v = *reinterpret_cast<const bf16x8*>(vgp + idx);
      int g = (nn >> 3) ^ (d & 7);
      *reinterpret_cast<bf16x8*>(&Vts[d * 512 + g * 8]) = v;
    }
  }
  const int w = tid >> 6, lane = tid & 63, c = lane & 15, quad = lane >> 4;
  const int rowq = seg * 256 + w * 32;  // queries rowq + rg*16 + c
  f32x4 x[2][2];  // [rg][tt]: query=rowq+rg*16+c, d=tt*16+quad*4+r
#pragma unroll
  for (int rg = 0; rg < 2; ++rg)
#pragma unroll
    for (int tt = 0; tt < 2; ++tt)
      x[rg][tt] = *reinterpret_cast<const f32x4*>(
          Q0 + (b * 512 + rowq + rg * 16 + c) * 256 + h * 32 + tt * 16 + quad * 4);
  __syncthreads();  // only barrier
  const f32x4 zf = {0.f, 0.f, 0.f, 0.f};
  bf16x8 ones;
#pragma unroll
  for (int j = 0; j < 8; ++j) ones[j] = (__bf16)1.0f;
#pragma unroll 1
  for (int layer = 0; layer < 4; ++layer) {
    // q B-frag straight from registers (d-perm matches Ks layout)
    bf16x8 aq[2];
#pragma unroll
    for (int rg = 0; rg < 2; ++rg) {
      aq[rg][0] = (__bf16)x[rg][0][0]; aq[rg][1] = (__bf16)x[rg][0][1];
      aq[rg][2] = (__bf16)x[rg][0][2]; aq[rg][3] = (__bf16)x[rg][0][3];
      aq[rg][4] = (__bf16)x[rg][1][0]; aq[rg][5] = (__bf16)x[rg][1][1];
      aq[rg][6] = (__bf16)x[rg][1][2]; aq[rg][7] = (__bf16)x[rg][1][3];
    }
    f32x4 sacc[2] = {zf, zf};   // row-sums via ones-MFMA (all rows identical)
    f32x4 O[2][2] = {{zf, zf}, {zf, zf}};
#pragma unroll
    for (int ch = 0; ch < 16; ++ch) {  // 32-key chunks, fully unrolled
      f32x4 S[2][2];  // S^T: row=key(quad*4+r), col=query(c)
#pragma unroll
      for (int tt = 0; tt < 2; ++tt) {
        int n = (ch * 2 + tt) * 16 + c;
        bf16x8 kf = *reinterpret_cast<const bf16x8*>(
            &Ks[n * 32 + ((quad ^ ((c >> 1) & 3)) << 3)]);
#pragma unroll
        for (int rg = 0; rg < 2; ++rg) S[rg][tt] = mfma16(kf, aq[rg], zf);
      }
      bf16x8 ap[2];
#pragma unroll
      for (int rg = 0; rg < 2; ++rg) {
#pragma unroll
        for (int tt = 0; tt < 2; ++tt)
#pragma unroll
          for (int r = 0; r < 4; ++r)
            S[rg][tt][r] = __builtin_amdgcn_exp2f(S[rg][tt][r]);
        ap[rg][0] = (__bf16)S[rg][0][0]; ap[rg][1] = (__bf16)S[rg][0][1];
        ap[rg][2] = (__bf16)S[rg][0][2]; ap[rg][3] = (__bf16)S[rg][0][3];
        ap[rg][4] = (__bf16)S[rg][1][0]; ap[rg][5] = (__bf16)S[rg][1][1];
        ap[rg][6] = (__bf16)S[rg][1][2]; ap[rg][7] = (__bf16)S[rg][1][3];
        sacc[rg] = mfma16(ones, ap[rg], sacc[rg]);  // softmax denom on MFMA pipe
      }
#pragma unroll
      for (int tt = 0; tt < 2; ++tt) {
        int d = tt * 16 + c;
        int gv = (ch * 4 + quad) ^ (c & 7);
        bf16x8 vf = *reinterpret_cast<const bf16x8*>(&Vts[d * 512 + gv * 8]);
#pragma unroll
        for (int rg = 0; rg < 2; ++rg) O[rg][tt] = mfma16(vf, ap[rg], O[rg][tt]);
      }
    }
#pragma unroll
    for (int rg = 0; rg < 2; ++rg) {
      float inv = __builtin_amdgcn_rcpf(sacc[rg][0]);  // every lane: own query
#pragma unroll
      for (int tt = 0; tt < 2; ++tt)
#pragma unroll
        for (int r = 0; r < 4; ++r) x[rg][tt][r] += O[rg][tt][r] * inv;
    }
  }
#pragma unroll
  for (int rg = 0; rg < 2; ++rg)
#pragma unroll
    for (int tt = 0; tt < 2; ++tt)
      *reinterpret_cast<f32x4*>(
          Out + (b * 512 + rowq + rg * 16 + c) * 256 + h * 32 + tt * 16 + quad * 4) = x[rg][tt];
}

extern "C" void kernel_launch(void* const* d_in, const int* in_sizes, int n_in,
                              void* d_out, int out_size, void* d_ws, size_t ws_size,
                              hipStream_t stream) {
  const float* X  = (const float*)d_in[0];
  const float* Wq = (const float*)d_in[1];
  const float* bq = (const float*)d_in[2];
  const float* Wk = (const float*)d_in[3];
  const float* bk = (const float*)d_in[4];
  const float* Wv = (const float*)d_in[5];
  const float* bv = (const float*)d_in[6];
  char* ws = (char*)d_ws;
  unsigned short* Wf   = (unsigned short*)(ws);                    // 393216 B
  float*          bias = (float*)(ws + 393216);                    // 3072 B
  unsigned short* Kb   = (unsigned short*)(ws + 397312);           // 8 MB
  unsigned short* Vt   = (unsigned short*)(ws + 397312 + 8388608); // 8 MB
  float* out = (float*)d_out;  // Q buffer first, final output after attn
  prep_kernel<<<97, 256, 0, stream>>>(Wq, bq, Wk, bk, Wv, bv, Wf, bias);
  qkv_kernel<<<512, 512, 0, stream>>>(X, Wf, bias, out, Kb, Vt);
  attn_kernel<<<512, 512, 0, stream>>>(out, Kb, Vt, out);
}

// Round 5
// 132.811 us; speedup vs baseline: 2.0194x; 2.0194x over previous
//
#include <hip/hip_runtime.h>

typedef __bf16 bf16x8 __attribute__((ext_vector_type(8)));
typedef float  f32x4  __attribute__((ext_vector_type(4)));

#define K_SCALE 0.25505402682247326f  // log2(e)/sqrt(32), folded into Wk/bk

static __device__ __forceinline__ unsigned short f2bf(float f) {
  return __builtin_bit_cast(unsigned short, (__bf16)f);
}
static __device__ __forceinline__ f32x4 mfma16(bf16x8 a, bf16x8 b, f32x4 c) {
  return __builtin_amdgcn_mfma_f32_16x16x32_bf16(a, b, c, 0, 0, 0);
}

// ---- prep: W -> bf16 in MFMA B-fragment order (K pre-scaled); bias concat --
__global__ __launch_bounds__(256) void prep_kernel(
    const float* __restrict__ Wq, const float* __restrict__ bq,
    const float* __restrict__ Wk, const float* __restrict__ bk,
    const float* __restrict__ Wv, const float* __restrict__ bv,
    unsigned short* __restrict__ Wf, float* __restrict__ bias) {
  if (blockIdx.x == 96) {
    int t = threadIdx.x;
#pragma unroll
    for (int kseg = 0; kseg < 3; ++kseg) {
      int i = kseg * 256 + t;
      float bb;
      if (i < 256)      bb = bq[i];
      else if (i < 512) bb = bk[i - 256] * K_SCALE;
      else              bb = bv[i - 512];
      bias[i] = bb;
    }
    return;
  }
  int fidx = blockIdx.x * 256 + threadIdx.x;  // < 24576
  int lane = fidx & 63;
  int ks = (fidx >> 6) & 7;
  int ct = fidx >> 9;
  int n = ct * 16 + (lane & 15);
  int kk = ks * 32 + (lane >> 4) * 8;
  const float* src;
  float scale = 1.0f;
  if (n < 256)      src = Wq + n * 256 + kk;
  else if (n < 512) { src = Wk + (n - 256) * 256 + kk; scale = K_SCALE; }
  else              src = Wv + (n - 512) * 256 + kk;
  float4 f0 = reinterpret_cast<const float4*>(src)[0];
  float4 f1 = reinterpret_cast<const float4*>(src)[1];
  bf16x8 h;
  h[0] = (__bf16)(f0.x * scale); h[1] = (__bf16)(f0.y * scale);
  h[2] = (__bf16)(f0.z * scale); h[3] = (__bf16)(f0.w * scale);
  h[4] = (__bf16)(f1.x * scale); h[5] = (__bf16)(f1.y * scale);
  h[6] = (__bf16)(f1.z * scale); h[7] = (__bf16)(f1.w * scale);
  *reinterpret_cast<bf16x8*>(Wf + fidx * 8) = h;
}

// ---- qkv: C[16384x768] = X @ W^T. Q->fp32 d_out; K->[bh][n][pd] bf16;
//      V->[bh][d][pn] bf16. Wave = 32 rows x 6 col-tiles. ---------------------
__global__ __launch_bounds__(512, 4) void qkv_kernel(
    const float* __restrict__ X, const unsigned short* __restrict__ Wf,
    const float* __restrict__ bias, float* __restrict__ Qout,
    unsigned short* __restrict__ Kb, unsigned short* __restrict__ Vt) {
  __shared__ __align__(16) unsigned short Alds[32 * 256];
  const int tid = threadIdx.x;
  const int rowbase = blockIdx.x * 32;
  {  // stage A tile 32x256 fp32->bf16, XOR chunk swizzle
    int idx = tid * 16;
    int r = idx >> 8, k = idx & 255;
    const float4* src = reinterpret_cast<const float4*>(X + (rowbase + r) * 256 + k);
    float4 f0 = src[0], f1 = src[1], f2 = src[2], f3 = src[3];
    bf16x8 h0, h1;
    h0[0]=(__bf16)f0.x; h0[1]=(__bf16)f0.y; h0[2]=(__bf16)f0.z; h0[3]=(__bf16)f0.w;
    h0[4]=(__bf16)f1.x; h0[5]=(__bf16)f1.y; h0[6]=(__bf16)f1.z; h0[7]=(__bf16)f1.w;
    h1[0]=(__bf16)f2.x; h1[1]=(__bf16)f2.y; h1[2]=(__bf16)f2.z; h1[3]=(__bf16)f2.w;
    h1[4]=(__bf16)f3.x; h1[5]=(__bf16)f3.y; h1[6]=(__bf16)f3.z; h1[7]=(__bf16)f3.w;
    int c0 = k >> 3;
    int p0 = (c0 & 24) | ((c0 ^ r) & 7);
    int p1 = ((c0 + 1) & 24) | (((c0 + 1) ^ r) & 7);
    *reinterpret_cast<bf16x8*>(&Alds[r * 256 + p0 * 8]) = h0;
    *reinterpret_cast<bf16x8*>(&Alds[r * 256 + p1 * 8]) = h1;
  }
  __syncthreads();
  const int w = tid >> 6, lane = tid & 63, c = lane & 15, quad = lane >> 4;
  const f32x4 zf = {0.f, 0.f, 0.f, 0.f};
  for (int p = 0; p < 6; ++p) {
    int ct = w * 6 + p;
    f32x4 acc[2] = {zf, zf};
#pragma unroll
    for (int ks = 0; ks < 8; ++ks) {
      bf16x8 bf = *reinterpret_cast<const bf16x8*>(Wf + ((ct * 8 + ks) * 64 + lane) * 8);
#pragma unroll
      for (int mg = 0; mg < 2; ++mg) {
        int m = mg * 16 + c;
        int c8 = ks * 4 + quad;
        int ph = (c8 & 24) | ((c8 ^ m) & 7);
        bf16x8 af = *reinterpret_cast<const bf16x8*>(&Alds[m * 256 + ph * 8]);
        acc[mg] = mfma16(af, bf, acc[mg]);
      }
    }
    int col = ct * 16 + c;
    float bb = bias[col];
#pragma unroll
    for (int mg = 0; mg < 2; ++mg) {
      int growb = rowbase + mg * 16 + quad * 4;
      int b = growb >> 9, nrow = growb & 511;
      if (col < 256) {
#pragma unroll
        for (int r = 0; r < 4; ++r)
          Qout[(growb + r) * 256 + col] = acc[mg][r] + bb;
      } else if (col < 512) {
        int d = col & 31, hh = (col - 256) >> 5;
        int pd = ((d >> 2) & 3) * 8 + ((d >> 4) & 1) * 4 + (d & 3);
#pragma unroll
        for (int r = 0; r < 4; ++r)
          Kb[((b * 8 + hh) * 512 + nrow + r) * 32 + pd] = f2bf(acc[mg][r] + bb);
      } else {
        int d = col & 31, hh = (col - 512) >> 5;
        // key perm: pn = (n&~31) + ((n>>2)&3)*8 + ((n>>4)&1)*4 + (n&3)
        int pnb = (nrow & ~31) + ((nrow >> 2) & 3) * 8 + ((nrow >> 4) & 1) * 4;
        ushort4 pk;
        pk.x = f2bf(acc[mg][0] + bb); pk.y = f2bf(acc[mg][1] + bb);
        pk.z = f2bf(acc[mg][2] + bb); pk.w = f2bf(acc[mg][3] + bb);
        *reinterpret_cast<ushort4*>(&Vt[((b * 8 + hh) * 32 + d) * 512 + pnb]) = pk;
      }
    }
  }
}

// ---- attn: 4 fused layers, transposed MFMA, register-resident state. -------
// grid: 256 bh x 2 segs, 8 waves x 32 queries.
__global__ __launch_bounds__(512, 4) void attn_kernel(
    const float* Q0, const unsigned short* __restrict__ Kg,
    const unsigned short* __restrict__ Vg, float* Out) {
  __shared__ __align__(16) unsigned short Ks[16384];   // [n][slot] 32/row, swz
  __shared__ __align__(16) unsigned short Vts[16384];  // [d][pn] 512/row, swz
  const int tid = threadIdx.x;
  const int bh = blockIdx.x >> 1, seg = blockIdx.x & 1;
  const int b = bh >> 3, h = bh & 7;
  const unsigned short* kgp = Kg + bh * 16384;
  const unsigned short* vgp = Vg + bh * 16384;
#pragma unroll
  for (int it = 0; it < 4; ++it) {
    int idx = it * 4096 + tid * 8;
    {
      int n = idx >> 5, g = (idx >> 3) & 3;
      bf16x8 v = *reinterpret_cast<const bf16x8*>(kgp + idx);
      // slot = g ^ ((n>>1)&3): per 16-lane read phase covers all 8 bank
      // groups exactly twice (2-way = free).
      *reinterpret_cast<bf16x8*>(&Ks[n * 32 + ((g ^ ((n >> 1) & 3)) << 3)]) = v;
    }
    {
      int d = idx >> 9, nn = idx & 511;
      bf16x8 v = *reinterpret_cast<const bf16x8*>(vgp + idx);
      int g = (nn >> 3) ^ (d & 7);
      *reinterpret_cast<bf16x8*>(&Vts[d * 512 + g * 8]) = v;
    }
  }
  const int w = tid >> 6, lane = tid & 63, c = lane & 15, quad = lane >> 4;
  const int rowq = seg * 256 + w * 32;  // queries rowq + rg*16 + c
  f32x4 x[2][2];  // [rg][tt]: query=rowq+rg*16+c, d=tt*16+quad*4+r
#pragma unroll
  for (int rg = 0; rg < 2; ++rg)
#pragma unroll
    for (int tt = 0; tt < 2; ++tt)
      x[rg][tt] = *reinterpret_cast<const f32x4*>(
          Q0 + (b * 512 + rowq + rg * 16 + c) * 256 + h * 32 + tt * 16 + quad * 4);
  __syncthreads();  // only barrier
  const f32x4 zf = {0.f, 0.f, 0.f, 0.f};
  bf16x8 ones;
#pragma unroll
  for (int j = 0; j < 8; ++j) ones[j] = (__bf16)1.0f;
#pragma unroll 1
  for (int layer = 0; layer < 4; ++layer) {
    // q B-frag straight from registers (d-perm matches Ks layout)
    bf16x8 aq[2];
#pragma unroll
    for (int rg = 0; rg < 2; ++rg) {
      aq[rg][0] = (__bf16)x[rg][0][0]; aq[rg][1] = (__bf16)x[rg][0][1];
      aq[rg][2] = (__bf16)x[rg][0][2]; aq[rg][3] = (__bf16)x[rg][0][3];
      aq[rg][4] = (__bf16)x[rg][1][0]; aq[rg][5] = (__bf16)x[rg][1][1];
      aq[rg][6] = (__bf16)x[rg][1][2]; aq[rg][7] = (__bf16)x[rg][1][3];
    }
    f32x4 sacc[2] = {zf, zf};   // row-sums via ones-MFMA (all rows identical)
    f32x4 O[2][2] = {{zf, zf}, {zf, zf}};
#pragma unroll 4
    for (int ch = 0; ch < 16; ++ch) {  // 32-key chunks; unroll 4 (16 spills!)
      f32x4 S[2][2];  // S^T: row=key(quad*4+r), col=query(c)
#pragma unroll
      for (int tt = 0; tt < 2; ++tt) {
        int n = (ch * 2 + tt) * 16 + c;
        bf16x8 kf = *reinterpret_cast<const bf16x8*>(
            &Ks[n * 32 + ((quad ^ ((c >> 1) & 3)) << 3)]);
#pragma unroll
        for (int rg = 0; rg < 2; ++rg) S[rg][tt] = mfma16(kf, aq[rg], zf);
      }
      bf16x8 ap[2];
#pragma unroll
      for (int rg = 0; rg < 2; ++rg) {
#pragma unroll
        for (int tt = 0; tt < 2; ++tt)
#pragma unroll
          for (int r = 0; r < 4; ++r)
            S[rg][tt][r] = __builtin_amdgcn_exp2f(S[rg][tt][r]);
        ap[rg][0] = (__bf16)S[rg][0][0]; ap[rg][1] = (__bf16)S[rg][0][1];
        ap[rg][2] = (__bf16)S[rg][0][2]; ap[rg][3] = (__bf16)S[rg][0][3];
        ap[rg][4] = (__bf16)S[rg][1][0]; ap[rg][5] = (__bf16)S[rg][1][1];
        ap[rg][6] = (__bf16)S[rg][1][2]; ap[rg][7] = (__bf16)S[rg][1][3];
        sacc[rg] = mfma16(ones, ap[rg], sacc[rg]);  // softmax denom on MFMA pipe
      }
#pragma unroll
      for (int tt = 0; tt < 2; ++tt) {
        int d = tt * 16 + c;
        int gv = (ch * 4 + quad) ^ (c & 7);
        bf16x8 vf = *reinterpret_cast<const bf16x8*>(&Vts[d * 512 + gv * 8]);
#pragma unroll
        for (int rg = 0; rg < 2; ++rg) O[rg][tt] = mfma16(vf, ap[rg], O[rg][tt]);
      }
    }
#pragma unroll
    for (int rg = 0; rg < 2; ++rg) {
      float inv = __builtin_amdgcn_rcpf(sacc[rg][0]);  // every lane: own query
#pragma unroll
      for (int tt = 0; tt < 2; ++tt)
#pragma unroll
        for (int r = 0; r < 4; ++r) x[rg][tt][r] += O[rg][tt][r] * inv;
    }
  }
#pragma unroll
  for (int rg = 0; rg < 2; ++rg)
#pragma unroll
    for (int tt = 0; tt < 2; ++tt)
      *reinterpret_cast<f32x4*>(
          Out + (b * 512 + rowq + rg * 16 + c) * 256 + h * 32 + tt * 16 + quad * 4) = x[rg][tt];
}

extern "C" void kernel_launch(void* const* d_in, const int* in_sizes, int n_in,
                              void* d_out, int out_size, void* d_ws, size_t ws_size,
                              hipStream_t stream) {
  const float* X  = (const float*)d_in[0];
  const float* Wq = (const float*)d_in[1];
  const float* bq = (const float*)d_in[2];
  const float* Wk = (const float*)d_in[3];
  const float* bk = (const float*)d_in[4];
  const float* Wv = (const float*)d_in[5];
  const float* bv = (const float*)d_in[6];
  char* ws = (char*)d_ws;
  unsigned short* Wf   = (unsigned short*)(ws);                    // 393216 B
  float*          bias = (float*)(ws + 393216);                    // 3072 B
  unsigned short* Kb   = (unsigned short*)(ws + 397312);           // 8 MB
  unsigned short* Vt   = (unsigned short*)(ws + 397312 + 8388608); // 8 MB
  float* out = (float*)d_out;  // Q buffer first, final output after attn
  prep_kernel<<<97, 256, 0, stream>>>(Wq, bq, Wk, bk, Wv, bv, Wf, bias);
  qkv_kernel<<<512, 512, 0, stream>>>(X, Wf, bias, out, Kb, Vt);
  attn_kernel<<<512, 512, 0, stream>>>(out, Kb, Vt, out);
}